// Round 1
// baseline (14239.864 us; speedup 1.0000x reference)
//
#include <hip/hip_runtime.h>
#include <math.h>

#define NB 256
#define NT 512
#define B_ 32
#define T_ 512
#define I_ 256
#define H_ 512
#define WPITCH 772          // 768 + 4 pad (bank decorrelation)
#define RSLOT 16            // h slot rotation depth == fence window

// ---------------- prepass: x[B][T][I] -> xT[T][I][B] ----------------
__global__ __launch_bounds__(256) void transpose_x(const float* __restrict__ x,
                                                   float* __restrict__ xT) {
    __shared__ float tile[B_][I_ + 4];
    const int t = blockIdx.x;
    const int tid = threadIdx.x;
    // load 32 rows of 256 (float4, coalesced per row)
    for (int idx = tid; idx < B_ * (I_ / 4); idx += 256) {
        const int b = idx >> 6;        // 64 float4 per row
        const int j = idx & 63;
        const float4 v = *reinterpret_cast<const float4*>(x + ((size_t)b * T_ + t) * I_ + 4 * j);
        tile[b][4 * j + 0] = v.x; tile[b][4 * j + 1] = v.y;
        tile[b][4 * j + 2] = v.z; tile[b][4 * j + 3] = v.w;
    }
    __syncthreads();
    // write xT[t][i][b] coalesced over b
    for (int idx = tid; idx < I_ * B_; idx += 256) {
        const int i = idx >> 5;
        const int b = idx & 31;
        xT[((size_t)t * I_ + i) * B_ + b] = tile[b][i];
    }
}

// ---------------- helpers ----------------
__device__ __forceinline__ float sigm(float v)  { return 1.0f / (1.0f + __expf(-v)); }
__device__ __forceinline__ float tanhf_(float v){ return 2.0f / (1.0f + __expf(-2.0f * v)) - 1.0f; }

template <int N>
__device__ __forceinline__ void dotn(const float* __restrict__ A,   // [k][b], already offset to b0
                                     const float* __restrict__ w,   // LDS weight row, offset to k0
                                     float& a0, float& a1, float& a2, float& a3) {
#pragma unroll 6
    for (int kc = 0; kc < N; ++kc) {
        const float4 w4 = *reinterpret_cast<const float4*>(w + 4 * kc);
        const float4 r0 = *reinterpret_cast<const float4*>(A + (size_t)(4 * kc + 0) * B_);
        const float4 r1 = *reinterpret_cast<const float4*>(A + (size_t)(4 * kc + 1) * B_);
        const float4 r2 = *reinterpret_cast<const float4*>(A + (size_t)(4 * kc + 2) * B_);
        const float4 r3 = *reinterpret_cast<const float4*>(A + (size_t)(4 * kc + 3) * B_);
        a0 = fmaf(w4.x, r0.x, a0); a1 = fmaf(w4.x, r0.y, a1); a2 = fmaf(w4.x, r0.z, a2); a3 = fmaf(w4.x, r0.w, a3);
        a0 = fmaf(w4.y, r1.x, a0); a1 = fmaf(w4.y, r1.y, a1); a2 = fmaf(w4.y, r1.z, a2); a3 = fmaf(w4.y, r1.w, a3);
        a0 = fmaf(w4.z, r2.x, a0); a1 = fmaf(w4.z, r2.y, a1); a2 = fmaf(w4.z, r2.z, a2); a3 = fmaf(w4.z, r2.w, a3);
        a0 = fmaf(w4.w, r3.x, a0); a1 = fmaf(w4.w, r3.y, a1); a2 = fmaf(w4.w, r3.z, a2); a3 = fmaf(w4.w, r3.w, a3);
    }
}

// ---------------- main persistent cooperative kernel ----------------
__global__ __launch_bounds__(NT, 2) void bilstm_kernel(
    const float* __restrict__ Wih_f, const float* __restrict__ Whh_f, const float* __restrict__ bias_f,
    const float* __restrict__ Wih_b, const float* __restrict__ Whh_b, const float* __restrict__ bias_b,
    float* __restrict__ out, float* __restrict__ ws) {

    __shared__ float sW[2 * 8 * WPITCH];     // 49,408 B: 16 gate rows x 768 (+pad)
    __shared__ float sRed[8][8 * 36];        // 9,216 B: slice x (row x batch, padded)
    __shared__ float sGates[256];            // 1,024 B

    const int tid = threadIdx.x;
    const int J = blockIdx.x;                // hidden pair owner: hq in {2J, 2J+1}

    const float* xT = ws;                                        // [T][I][B]
    float* hs = ws + (size_t)T_ * I_ * B_;                       // [2][RSLOT][H][B]
    unsigned* bar = reinterpret_cast<unsigned*>(hs + (size_t)2 * RSLOT * H_ * B_);  // [2][T]

    // ---- stage weights into LDS (once): row r -> gate g=r>>1, q=r&1, gr = g*H + 2J+q
    for (int idx = tid; idx < 3072; idx += NT) {                 // 3072 float4s
        const int d = (idx >= 1536) ? 1 : 0;
        const int rem = idx - d * 1536;
        const int r = rem / 192;
        const int c = 4 * (rem - r * 192);
        const int gr = (r >> 1) * H_ + 2 * J + (r & 1);
        const float* src;
        if (c < I_) {
            const float* Wih = d ? Wih_b : Wih_f;
            src = Wih + (size_t)gr * I_ + c;
        } else {
            const float* Whh = d ? Whh_b : Whh_f;
            src = Whh + (size_t)gr * H_ + (c - I_);
        }
        *reinterpret_cast<float4*>(&sW[(d * 8 + r) * WPITCH + c]) = *reinterpret_cast<const float4*>(src);
    }

    // dot-phase mapping
    const int bg = tid & 7;                  // batch group (4 batches)
    const int rr = (tid >> 3) & 7;           // gate row 0..7
    const int sl = tid >> 6;                 // k-slice 0..7 (uniform per wave)
    const int b0 = 4 * bg;
    const int k0 = 96 * sl;

    float c_state[2] = {0.f, 0.f};
    float my_bias[2] = {0.f, 0.f};
    if (tid < 256) {
        const int r = tid >> 5;
        const int gr = (r >> 1) * H_ + 2 * J + (r & 1);
        my_bias[0] = bias_f[gr];
        my_bias[1] = bias_b[gr];
    }
    __syncthreads();

    for (int t = 0; t < T_; ++t) {
#pragma unroll
        for (int d = 0; d < 2; ++d) {
            // ---- wait for h(t-1) of this direction (skip at t=0: slots pre-zeroed)
            if (tid == 0) {
                if (t > 0) {
                    while (__hip_atomic_load(&bar[d * T_ + (t - 1)], __ATOMIC_RELAXED,
                                             __HIP_MEMORY_SCOPE_AGENT) < NB)
                        __builtin_amdgcn_s_sleep(1);
                }
                // windowed full fence: invalidate stale L1/L2 lines once per slot-reuse window
                if (d == 0 && (t & (RSLOT - 1)) == 0) __threadfence();
            }
            __syncthreads();

            const int tx = d ? (T_ - 1 - t) : t;
            const float* hsrc = hs + ((size_t)(d * RSLOT + ((t + RSLOT - 1) & (RSLOT - 1))) * H_) * B_;
            const float* xbase = xT + ((size_t)tx * I_) * B_;
            const float* wbase = sW + (8 * d + rr) * WPITCH + k0;

            float a0 = 0.f, a1 = 0.f, a2 = 0.f, a3 = 0.f;
            if (sl < 2) {
                dotn<24>(xbase + (size_t)k0 * B_ + b0, wbase, a0, a1, a2, a3);
            } else if (sl == 2) {
                dotn<16>(xbase + (size_t)192 * B_ + b0, wbase, a0, a1, a2, a3);
                dotn<8>(hsrc + b0, wbase + 64, a0, a1, a2, a3);
            } else {
                dotn<24>(hsrc + (size_t)(k0 - I_) * B_ + b0, wbase, a0, a1, a2, a3);
            }
            *reinterpret_cast<float4*>(&sRed[sl][rr * 36 + b0]) = make_float4(a0, a1, a2, a3);
            __syncthreads();

            // ---- reduce 8 k-slices, add bias
            if (tid < 256) {
                const int r = tid >> 5, b = tid & 31;
                float s = my_bias[d];
#pragma unroll
                for (int z = 0; z < 8; ++z) s += sRed[z][r * 36 + b];
                sGates[r * 32 + b] = s;
            }
            __syncthreads();

            // ---- LSTM cell update for the 2 owned hidden columns x 32 batches
            if (tid < 64) {
                const int q = tid >> 5, b = tid & 31;
                const float gi = sGates[(0 + q) * 32 + b];
                const float gf = sGates[(2 + q) * 32 + b];
                const float gg = sGates[(4 + q) * 32 + b];
                const float go = sGates[(6 + q) * 32 + b];
                const float iv = sigm(gi), fv = sigm(gf), gv = tanhf_(gg), ov = sigm(go);
                const float c = fv * c_state[d] + iv * gv;
                c_state[d] = c;
                const float h = ov * tanhf_(c);
                const int hq = 2 * J + q;
                hs[((size_t)(d * RSLOT + (t & (RSLOT - 1))) * H_ + hq) * B_ + b] = h;
                out[((size_t)b * T_ + tx) * (2 * H_) + d * H_ + hq] = h;
            }
            __syncthreads();   // drain stores (compiler emits vmcnt(0) before s_barrier)

            // ---- release: wbl2 + device-visible arrival
            if (tid == 0) {
                __hip_atomic_fetch_add(&bar[d * T_ + t], 1u, __ATOMIC_RELEASE,
                                       __HIP_MEMORY_SCOPE_AGENT);
            }
        }
    }
}

extern "C" void kernel_launch(void* const* d_in, const int* in_sizes, int n_in,
                              void* d_out, int out_size, void* d_ws, size_t ws_size,
                              hipStream_t stream) {
    const float* x     = (const float*)d_in[0];
    const float* Wih_f = (const float*)d_in[1];
    const float* Whh_f = (const float*)d_in[2];
    const float* b_f   = (const float*)d_in[3];
    const float* Wih_b = (const float*)d_in[4];
    const float* Whh_b = (const float*)d_in[5];
    const float* b_b   = (const float*)d_in[6];
    float* out = (float*)d_out;
    float* ws  = (float*)d_ws;

    const size_t xt_bytes  = (size_t)T_ * I_ * B_ * 4;          // 16 MB
    const size_t hs_bytes  = (size_t)2 * RSLOT * H_ * B_ * 4;   // 4 MB
    const size_t bar_bytes = (size_t)2 * T_ * sizeof(unsigned); // 4 KB

    // zero h slots + barrier counters every launch (ws is poisoned 0xAA)
    hipMemsetAsync((char*)d_ws + xt_bytes, 0, hs_bytes + bar_bytes, stream);

    hipLaunchKernelGGL(transpose_x, dim3(T_), dim3(256), 0, stream, x, ws);

    void* args[] = { (void*)&Wih_f, (void*)&Whh_f, (void*)&b_f,
                     (void*)&Wih_b, (void*)&Whh_b, (void*)&b_b,
                     (void*)&out,   (void*)&ws };
    hipLaunchCooperativeKernel((void*)bilstm_kernel, dim3(NB), dim3(NT), args, 0, stream);
}

// Round 2
// 6184.994 us; speedup vs baseline: 2.3023x; 2.3023x over previous
//
#include <hip/hip_runtime.h>
#include <math.h>

#define NBLK 256
#define PD   128           // blocks per direction
#define NT   512
#define B_   32
#define T_   512
#define I_   256
#define H_   512
#define WPITCH 772         // 768 + 4 pad
#define RSLOT 16           // h slot rotation depth == fence window
#define GRP  4             // arrival counter groups per (dir,t)
#define GTH  (PD/GRP)      // 32 arrivals per group

// ---------------- prepass: x[B][T][I] -> xT[T][I][B] ----------------
__global__ __launch_bounds__(256) void transpose_x(const float* __restrict__ x,
                                                   float* __restrict__ xT) {
    __shared__ float tile[B_][I_ + 4];
    const int t = blockIdx.x;
    const int tid = threadIdx.x;
    for (int idx = tid; idx < B_ * (I_ / 4); idx += 256) {
        const int b = idx >> 6;
        const int j = idx & 63;
        const float4 v = *reinterpret_cast<const float4*>(x + ((size_t)b * T_ + t) * I_ + 4 * j);
        tile[b][4 * j + 0] = v.x; tile[b][4 * j + 1] = v.y;
        tile[b][4 * j + 2] = v.z; tile[b][4 * j + 3] = v.w;
    }
    __syncthreads();
    for (int idx = tid; idx < I_ * B_; idx += 256) {
        const int i = idx >> 5;
        const int b = idx & 31;
        xT[((size_t)t * I_ + i) * B_ + b] = tile[b][i];
    }
}

// ---------------- helpers ----------------
__device__ __forceinline__ float sigm(float v)  { return 1.0f / (1.0f + __expf(-v)); }
__device__ __forceinline__ float tanhf_(float v){ return 2.0f / (1.0f + __expf(-2.0f * v)) - 1.0f; }

template <int N>
__device__ __forceinline__ void dotn(const float* __restrict__ A,   // [k][b] layout, offset to b0
                                     const float* __restrict__ w,   // LDS weight row, offset to k0
                                     float& a0, float& a1, float& a2, float& a3) {
#pragma unroll 4
    for (int kc = 0; kc < N; ++kc) {
        const float4 w4 = *reinterpret_cast<const float4*>(w + 4 * kc);
        const float4 r0 = *reinterpret_cast<const float4*>(A + (size_t)(4 * kc + 0) * B_);
        const float4 r1 = *reinterpret_cast<const float4*>(A + (size_t)(4 * kc + 1) * B_);
        const float4 r2 = *reinterpret_cast<const float4*>(A + (size_t)(4 * kc + 2) * B_);
        const float4 r3 = *reinterpret_cast<const float4*>(A + (size_t)(4 * kc + 3) * B_);
        a0 = fmaf(w4.x, r0.x, a0); a1 = fmaf(w4.x, r0.y, a1); a2 = fmaf(w4.x, r0.z, a2); a3 = fmaf(w4.x, r0.w, a3);
        a0 = fmaf(w4.y, r1.x, a0); a1 = fmaf(w4.y, r1.y, a1); a2 = fmaf(w4.y, r1.z, a2); a3 = fmaf(w4.y, r1.w, a3);
        a0 = fmaf(w4.z, r2.x, a0); a1 = fmaf(w4.z, r2.y, a1); a2 = fmaf(w4.z, r2.z, a2); a3 = fmaf(w4.z, r2.w, a3);
        a0 = fmaf(w4.w, r3.x, a0); a1 = fmaf(w4.w, r3.y, a1); a2 = fmaf(w4.w, r3.z, a2); a3 = fmaf(w4.w, r3.w, a3);
    }
}

// ---------------- main persistent cooperative kernel ----------------
// One direction per block: blockIdx&1 = dir, blockIdx>>1 = Jh (owns hq = 4Jh..4Jh+3).
__global__ __launch_bounds__(NT, 2) void bilstm_kernel(
    const float* __restrict__ Wih_f, const float* __restrict__ Whh_f, const float* __restrict__ bias_f,
    const float* __restrict__ Wih_b, const float* __restrict__ Whh_b, const float* __restrict__ bias_b,
    float* __restrict__ out, float* __restrict__ ws) {

    __shared__ float sW[16 * WPITCH];        // 49,408 B: 16 gate rows x 768 (+pad)
    __shared__ float sRed[4][16 * 36];       // 9,216 B
    __shared__ float sGates[16 * 32];        // 2,048 B
    __shared__ float sH[4 * 32];             //   512 B

    const int tid = threadIdx.x;
    const int d   = blockIdx.x & 1;
    const int Jh  = blockIdx.x >> 1;         // 0..127

    const float* xT = ws;                                        // [T][I][B]
    float* hs = ws + (size_t)T_ * I_ * B_;                       // [2][RSLOT][H][B]
    unsigned* bar = reinterpret_cast<unsigned*>(hs + (size_t)2 * RSLOT * H_ * B_);  // [2][T][GRP]

    const float* Wih = d ? Wih_b : Wih_f;
    const float* Whh = d ? Whh_b : Whh_f;
    const float* bia = d ? bias_b : bias_f;

    // ---- stage weights into LDS (once): 16 rows x 768; row r -> gr = (r>>2)*H + 4Jh + (r&3)
    for (int idx = tid; idx < 16 * 192; idx += NT) {
        const int r = idx / 192;
        const int c = 4 * (idx - r * 192);
        const int gr = (r >> 2) * H_ + 4 * Jh + (r & 3);
        const float* src = (c < I_) ? (Wih + (size_t)gr * I_ + c)
                                    : (Whh + (size_t)gr * H_ + (c - I_));
        *reinterpret_cast<float4*>(&sW[r * WPITCH + c]) = *reinterpret_cast<const float4*>(src);
    }

    // dot-phase mapping: tid = bg(3b) | rr(4b) | sl(2b)
    const int bg = tid & 7;
    const int rr = (tid >> 3) & 15;          // gate row 0..15
    const int sl = tid >> 7;                 // k-slice 0..3
    const int b0 = 4 * bg;

    const int r_red = tid >> 5;              // 0..15
    const int b_red = tid & 31;
    const float my_bias = bia[(r_red >> 2) * H_ + 4 * Jh + (r_red & 3)];

    float c_state = 0.f;
    __syncthreads();

    for (int t = 0; t < T_; ++t) {
        const int tx = d ? (T_ - 1 - t) : t;
        const float* wrow = sW + rr * WPITCH;

        // ---- x-projection part first: overlaps barrier propagation latency
        float a0 = 0.f, a1 = 0.f, a2 = 0.f, a3 = 0.f;
        dotn<16>(xT + ((size_t)tx * I_ + 64 * sl) * B_ + b0, wrow + 64 * sl, a0, a1, a2, a3);

        // ---- wait for h(t-1) of this direction
        if (t > 0) {
            if (tid < GRP) {
                unsigned* ctr = &bar[(((size_t)d * T_ + (t - 1)) << 2) + tid];
                while (__hip_atomic_load(ctr, __ATOMIC_RELAXED, __HIP_MEMORY_SCOPE_AGENT) < GTH)
                    __builtin_amdgcn_s_sleep(1);
            }
            // amortized cache hygiene: kill L1/L2 lines of the slot-rotation window
            if (tid == 0 && (t & (RSLOT - 1)) == 0) __threadfence();
        }
        __syncthreads();

        // ---- hh part (h(t-1) via cached float4 loads; slots rotate, fence re-arms window)
        if (t > 0) {
            const float* hsrc = hs + (size_t)((d * RSLOT + ((t - 1) & (RSLOT - 1))) * H_) * B_;
            dotn<32>(hsrc + (size_t)(128 * sl) * B_ + b0, wrow + I_ + 128 * sl, a0, a1, a2, a3);
        }
        *reinterpret_cast<float4*>(&sRed[sl][rr * 36 + b0]) = make_float4(a0, a1, a2, a3);
        __syncthreads();

        // ---- reduce 4 k-slices + bias
        float g = my_bias;
#pragma unroll
        for (int z = 0; z < 4; ++z) g += sRed[z][r_red * 36 + b_red];
        sGates[r_red * 32 + b_red] = g;
        __syncthreads();

        // ---- LSTM cell: 4 owned columns x 32 batches
        if (tid < 128) {
            const int q = tid >> 5, b = tid & 31;
            const float gi = sGates[(0 * 4 + q) * 32 + b];
            const float gf = sGates[(1 * 4 + q) * 32 + b];
            const float gg = sGates[(2 * 4 + q) * 32 + b];
            const float go = sGates[(3 * 4 + q) * 32 + b];
            const float iv = sigm(gi), fv = sigm(gf), gv = tanhf_(gg), ov = sigm(go);
            const float c = fv * c_state + iv * gv;
            c_state = c;
            const float h = ov * tanhf_(c);
            // write-through to L3 (agent scope, relaxed) — no wbl2 needed anywhere
            __hip_atomic_store(hs + (size_t)((d * RSLOT + (t & (RSLOT - 1))) * H_ + 4 * Jh + q) * B_ + b,
                               h, __ATOMIC_RELAXED, __HIP_MEMORY_SCOPE_AGENT);
            sH[q * 32 + b] = h;
        }
        __syncthreads();   // implicit vmcnt(0): h stores are at L3 before anyone arrives

        // ---- arrive (relaxed: ordering provided by the barrier drain above)
        if (tid == 0) {
            __hip_atomic_fetch_add(&bar[(((size_t)d * T_ + t) << 2) + (Jh & 3)], 1u,
                                   __ATOMIC_RELAXED, __HIP_MEMORY_SCOPE_AGENT);
        }
        // ---- output store (off the critical path, after arrive)
        if (tid < 32) {
            const float4 o4 = make_float4(sH[0 * 32 + tid], sH[1 * 32 + tid],
                                          sH[2 * 32 + tid], sH[3 * 32 + tid]);
            *reinterpret_cast<float4*>(&out[((size_t)tid * T_ + tx) * (2 * H_) + (size_t)d * H_ + 4 * Jh]) = o4;
        }
    }
}

extern "C" void kernel_launch(void* const* d_in, const int* in_sizes, int n_in,
                              void* d_out, int out_size, void* d_ws, size_t ws_size,
                              hipStream_t stream) {
    const float* x     = (const float*)d_in[0];
    const float* Wih_f = (const float*)d_in[1];
    const float* Whh_f = (const float*)d_in[2];
    const float* b_f   = (const float*)d_in[3];
    const float* Wih_b = (const float*)d_in[4];
    const float* Whh_b = (const float*)d_in[5];
    const float* b_b   = (const float*)d_in[6];
    float* out = (float*)d_out;
    float* ws  = (float*)d_ws;

    const size_t xt_bytes  = (size_t)T_ * I_ * B_ * 4;          // 16 MB
    const size_t hs_bytes  = (size_t)2 * RSLOT * H_ * B_ * 4;   // 2 MB
    const size_t bar_bytes = (size_t)2 * T_ * GRP * sizeof(unsigned); // 16 KB

    // only the barrier counters need zeroing (hs slot 0 is written before first read)
    hipMemsetAsync((char*)d_ws + xt_bytes + hs_bytes, 0, bar_bytes, stream);

    hipLaunchKernelGGL(transpose_x, dim3(T_), dim3(256), 0, stream, x, ws);

    void* args[] = { (void*)&Wih_f, (void*)&Whh_f, (void*)&b_f,
                     (void*)&Wih_b, (void*)&Whh_b, (void*)&b_b,
                     (void*)&out,   (void*)&ws };
    hipLaunchCooperativeKernel((void*)bilstm_kernel, dim3(NBLK), dim3(NT), args, 0, stream);
}

// Round 5
// 4088.826 us; speedup vs baseline: 3.4826x; 1.5127x over previous
//
#include <hip/hip_runtime.h>

#define B_    32
#define T_    512
#define I_    256
#define H_    512
#define PB    16          // blocks per direction
#define NBLK  32
#define NT    256
#define NSLOT 16          // h slot rotation depth == fence window

typedef __attribute__((ext_vector_type(8))) short  short8;
typedef __attribute__((ext_vector_type(4))) float  float4v;

__device__ __forceinline__ unsigned short f2bf(float f) {
    union { float f; unsigned u; } v; v.f = f;
    unsigned r = v.u + 0x7FFFu + ((v.u >> 16) & 1u);   // RTNE
    return (unsigned short)(r >> 16);
}

__device__ __forceinline__ short8 cvt8(const float* p) {
    float4 u = *reinterpret_cast<const float4*>(p);
    float4 v = *reinterpret_cast<const float4*>(p + 4);
    short8 r;
    r[0] = (short)f2bf(u.x); r[1] = (short)f2bf(u.y);
    r[2] = (short)f2bf(u.z); r[3] = (short)f2bf(u.w);
    r[4] = (short)f2bf(v.x); r[5] = (short)f2bf(v.y);
    r[6] = (short)f2bf(v.z); r[7] = (short)f2bf(v.w);
    return r;
}

__device__ __forceinline__ float sigm(float v)  { return 1.0f / (1.0f + __expf(-v)); }
__device__ __forceinline__ float tanhf_(float v){ return 2.0f / (1.0f + __expf(-2.0f * v)) - 1.0f; }

// ---------------- prepass: x[B][T][I] fp32 -> xfrag[T][chunk16][lane64][8] bf16 ----------------
// B-frag layout for mfma_16x16x32: chunk = kstep*2 + nh;
// lane lf holds (b = nh*16 + (lf&15), i = kstep*32 + (lf>>4)*8 + j), j=0..7.
__global__ __launch_bounds__(256) void build_xfrag(const float* __restrict__ x,
                                                   unsigned short* __restrict__ xf) {
    const int t = blockIdx.x, tid = threadIdx.x;
#pragma unroll
    for (int rep = 0; rep < 4; ++rep) {
        const int eidx  = rep * 256 + tid;          // 0..1023
        const int chunk = eidx >> 6, lf = eidx & 63;
        const int kstep = chunk >> 1, nh = chunk & 1;
        const int kq = lf >> 4, nm = lf & 15;
        const int b  = nh * 16 + nm;
        const int i0 = kstep * 32 + kq * 8;
        const float* src = x + ((size_t)b * T_ + t) * I_ + i0;
        short8 v = cvt8(src);
        *reinterpret_cast<short8*>(xf + ((size_t)t * 16 + chunk) * 512 + lf * 8) = v;
    }
}

// ---------------- main persistent kernel (plain launch; 32 blocks <= 256 CUs => co-resident) ----
// blockIdx: d = bx&1, pb = bx>>1. Block owns hid [32pb, 32pb+32), all 4 gates.
__global__ __launch_bounds__(NT, 1) void bilstm_mfma(
    const float* __restrict__ Wih_f, const float* __restrict__ Whh_f, const float* __restrict__ bias_f,
    const float* __restrict__ Wih_b, const float* __restrict__ Whh_b, const float* __restrict__ bias_b,
    float* __restrict__ out, float* __restrict__ ws) {

    __shared__ __align__(16) char sAX[16 * 1024];   // x B-frags, 16 chunks
    __shared__ __align__(16) char sAH[32 * 1024];   // h B-frags, 32 chunks

    const int tid  = threadIdx.x;
    const int lane = tid & 63;
    const int w    = tid >> 6;                       // wave 0..3
    const int d    = blockIdx.x & 1;
    const int pb   = blockIdx.x >> 1;                // 0..15

    const unsigned short* xfrag = (const unsigned short*)ws;                   // 8 MB
    unsigned* hfrag = (unsigned*)((char*)ws + (size_t)T_ * 16 * 1024);         // 1 MB, u32 view
    const char* hfrag_b = (const char*)hfrag;
    unsigned* bar = (unsigned*)((char*)hfrag + (size_t)2 * NSLOT * 32 * 1024); // [2][T]

    const float* Wih = d ? Wih_b : Wih_f;
    const float* Whh = d ? Whh_b : Whh_f;
    const float* bia = d ? bias_b : bias_f;

    // ---- one-time: weights -> resident A-fragments (bf16) ----
    // A-frag lane map: m = lane&15, k = (lane>>4)*8 + j.  m = hid_local*4 + gate.
    const int mA  = lane & 15;
    const int kqA = lane >> 4;
    const int gA  = mA & 3;
    const int gr0 = gA * H_ + 32 * pb + 8 * w + (mA >> 2);   // mt=0
    const int gr1 = gr0 + 4;                                  // mt=1

    short8 wx0[8], wx1[8], wh0[16], wh1[16];
#pragma unroll
    for (int kst = 0; kst < 8; ++kst) {
        wx0[kst] = cvt8(Wih + (size_t)gr0 * I_ + kst * 32 + kqA * 8);
        wx1[kst] = cvt8(Wih + (size_t)gr1 * I_ + kst * 32 + kqA * 8);
    }
#pragma unroll
    for (int kst = 0; kst < 16; ++kst) {
        wh0[kst] = cvt8(Whh + (size_t)gr0 * H_ + kst * 32 + kqA * 8);
        wh1[kst] = cvt8(Whh + (size_t)gr1 * H_ + kst * 32 + kqA * 8);
    }

    const int hid0 = 32 * pb + 8 * w + kqA;          // cell hid for mt=0
    float4v bq0, bq1;
#pragma unroll
    for (int g = 0; g < 4; ++g) {
        bq0[g] = bia[g * H_ + hid0];
        bq1[g] = bia[g * H_ + hid0 + 4];
    }

    float c00 = 0.f, c01 = 0.f, c10 = 0.f, c11 = 0.f;
    __syncthreads();

    for (int t = 0; t < T_; ++t) {
        const int tx    = d ? (T_ - 1 - t) : t;
        const int slot  = t & (NSLOT - 1);
        const int pslot = (t - 1) & (NSLOT - 1);

        // ---- 1. stage x frags via registers ----
        {
            const char* src = (const char*)xfrag + ((size_t)tx * 16 + w * 4) * 1024 + lane * 16;
            uint4 xbuf[4];
#pragma unroll
            for (int c = 0; c < 4; ++c) xbuf[c] = *reinterpret_cast<const uint4*>(src + c * 1024);
#pragma unroll
            for (int c = 0; c < 4; ++c)
                *reinterpret_cast<uint4*>(sAX + (w * 4 + c) * 1024 + lane * 16) = xbuf[c];
        }

        // ---- 2. wait for h(t-1); amortized cache hygiene (R2-proven scheme) ----
        if (t > 0 && tid == 0) {
            while (__hip_atomic_load(&bar[d * T_ + (t - 1)], __ATOMIC_RELAXED,
                                     __HIP_MEMORY_SCOPE_AGENT) < PB)
                __builtin_amdgcn_s_sleep(1);
            if ((t & (NSLOT - 1)) == 0) __threadfence();
        }
        __syncthreads();   // (A) sAX complete; h(t-1) globally visible

        // ---- 3a. issue h-frag global loads (8 chunks per wave) ----
        uint4 hbuf[8];
        if (t > 0) {
            const char* src = hfrag_b + ((size_t)(d * NSLOT + pslot) * 32 + w * 8) * 1024 + lane * 16;
#pragma unroll
            for (int c = 0; c < 8; ++c) hbuf[c] = *reinterpret_cast<const uint4*>(src + c * 1024);
        }

        // ---- 4. MFMA: x part (overlaps h-frag loads in flight) ----
        float4v a00 = bq0, a01 = bq0, a10 = bq1, a11 = bq1;
#pragma unroll
        for (int kst = 0; kst < 8; ++kst) {
            short8 f0 = *reinterpret_cast<const short8*>(sAX + (kst * 2 + 0) * 1024 + lane * 16);
            short8 f1 = *reinterpret_cast<const short8*>(sAX + (kst * 2 + 1) * 1024 + lane * 16);
            a00 = __builtin_amdgcn_mfma_f32_16x16x32_bf16(wx0[kst], f0, a00, 0, 0, 0);
            a01 = __builtin_amdgcn_mfma_f32_16x16x32_bf16(wx0[kst], f1, a01, 0, 0, 0);
            a10 = __builtin_amdgcn_mfma_f32_16x16x32_bf16(wx1[kst], f0, a10, 0, 0, 0);
            a11 = __builtin_amdgcn_mfma_f32_16x16x32_bf16(wx1[kst], f1, a11, 0, 0, 0);
        }

        // ---- 3b. write h frags to LDS ----
        if (t > 0) {
#pragma unroll
            for (int c = 0; c < 8; ++c)
                *reinterpret_cast<uint4*>(sAH + (w * 8 + c) * 1024 + lane * 16) = hbuf[c];
        }
        __syncthreads();   // (B) h frags staged

        // ---- 5. MFMA: h part ----
        if (t > 0) {
#pragma unroll
            for (int kst = 0; kst < 16; ++kst) {
                short8 f0 = *reinterpret_cast<const short8*>(sAH + (kst * 2 + 0) * 1024 + lane * 16);
                short8 f1 = *reinterpret_cast<const short8*>(sAH + (kst * 2 + 1) * 1024 + lane * 16);
                a00 = __builtin_amdgcn_mfma_f32_16x16x32_bf16(wh0[kst], f0, a00, 0, 0, 0);
                a01 = __builtin_amdgcn_mfma_f32_16x16x32_bf16(wh0[kst], f1, a01, 0, 0, 0);
                a10 = __builtin_amdgcn_mfma_f32_16x16x32_bf16(wh1[kst], f0, a10, 0, 0, 0);
                a11 = __builtin_amdgcn_mfma_f32_16x16x32_bf16(wh1[kst], f1, a11, 0, 0, 0);
            }
        }

        // ---- 6. LSTM cell (in-register; acc quad = 4 gates of one cell) ----
        float h00, h01, h10, h11;
        {
            float iv, fv, gv, ov, c;
            iv = sigm(a00[0]); fv = sigm(a00[1]); gv = tanhf_(a00[2]); ov = sigm(a00[3]);
            c = fv * c00 + iv * gv; c00 = c; h00 = ov * tanhf_(c);
            iv = sigm(a01[0]); fv = sigm(a01[1]); gv = tanhf_(a01[2]); ov = sigm(a01[3]);
            c = fv * c01 + iv * gv; c01 = c; h01 = ov * tanhf_(c);
            iv = sigm(a10[0]); fv = sigm(a10[1]); gv = tanhf_(a10[2]); ov = sigm(a10[3]);
            c = fv * c10 + iv * gv; c10 = c; h10 = ov * tanhf_(c);
            iv = sigm(a11[0]); fv = sigm(a11[1]); gv = tanhf_(a11[2]); ov = sigm(a11[3]);
            c = fv * c11 + iv * gv; c11 = c; h11 = ov * tanhf_(c);
        }

        // ---- 7. pack pairs (hid, hid+1) via partner lane (lane^16) and store ----
        const float p00 = __shfl_xor(h00, 16, 64);
        const float p01 = __shfl_xor(h01, 16, 64);
        const float p10 = __shfl_xor(h10, 16, 64);
        const float p11 = __shfl_xor(h11, 16, 64);

        if ((kqA & 1) == 0) {
            const int bn0 = lane & 15;
            const unsigned sb = (d * NSLOT + slot) * 32;
            float hv_[4] = { h00, h01, h10, h11 };
            float pv_[4] = { p00, p01, p10, p11 };
            int   hidv[4] = { hid0, hid0, hid0 + 4, hid0 + 4 };
            int   bv[4]   = { bn0, bn0 + 16, bn0, bn0 + 16 };
#pragma unroll
            for (int e = 0; e < 4; ++e) {
                const int hid = hidv[e], b = bv[e];
                const unsigned hpk = (unsigned)f2bf(hv_[e]) | ((unsigned)f2bf(pv_[e]) << 16);
                const int chunk = (hid >> 5) * 2 + (b >> 4);
                const int lf    = ((hid >> 3) & 3) * 16 + (b & 15);
                const unsigned idx = (sb + chunk) * 256 + lf * 4 + ((hid & 7) >> 1);
                __hip_atomic_store(hfrag + idx, hpk, __ATOMIC_RELAXED, __HIP_MEMORY_SCOPE_AGENT);
                *reinterpret_cast<float2*>(out + ((size_t)b * T_ + tx) * (2 * H_) + (size_t)d * H_ + hid)
                    = make_float2(hv_[e], pv_[e]);
            }
        }
        __syncthreads();   // (C) vmcnt(0) drain: h stores at coherence point before arrival

        // ---- 8. arrive ----
        if (tid == 0)
            __hip_atomic_fetch_add(&bar[d * T_ + t], 1u, __ATOMIC_RELAXED,
                                   __HIP_MEMORY_SCOPE_AGENT);
    }
}

extern "C" void kernel_launch(void* const* d_in, const int* in_sizes, int n_in,
                              void* d_out, int out_size, void* d_ws, size_t ws_size,
                              hipStream_t stream) {
    const float* x     = (const float*)d_in[0];
    const float* Wih_f = (const float*)d_in[1];
    const float* Whh_f = (const float*)d_in[2];
    const float* b_f   = (const float*)d_in[3];
    const float* Wih_b = (const float*)d_in[4];
    const float* Whh_b = (const float*)d_in[5];
    const float* b_b   = (const float*)d_in[6];
    float* out = (float*)d_out;

    const size_t xf_bytes = (size_t)T_ * 16 * 1024;          // 8 MB
    const size_t hf_bytes = (size_t)2 * NSLOT * 32 * 1024;   // 1 MB
    const size_t bar_bytes = (size_t)2 * T_ * sizeof(unsigned);

    hipMemsetAsync((char*)d_ws + xf_bytes + hf_bytes, 0, bar_bytes, stream);

    hipLaunchKernelGGL(build_xfrag, dim3(T_), dim3(256), 0, stream,
                       x, (unsigned short*)d_ws);

    // Plain launch (NOT cooperative): no CG grid-sync used; 32 blocks on 256 CUs
    // at 1 block/CU are trivially co-resident, and the inter-block barrier is a
    // hand-rolled device-scope atomic spin.
    hipLaunchKernelGGL(bilstm_mfma, dim3(NBLK), dim3(NT), 0, stream,
                       Wih_f, Whh_f, b_f, Wih_b, Whh_b, b_b, out, (float*)d_ws);
}

// Round 6
// 2407.280 us; speedup vs baseline: 5.9153x; 1.6985x over previous
//
#include <hip/hip_runtime.h>

#define B_    32
#define T_    512
#define I_    256
#define H_    512
#define PB    16          // blocks per direction
#define NBLK  32
#define NT    256
#define NSLOT 4           // h slot rotation (WAR slack only; no cache-staleness machinery)
#define HPITCH 34         // fp32 LDS h-transpose pitch (2-way banks = free)

typedef __attribute__((ext_vector_type(8))) short  short8;
typedef __attribute__((ext_vector_type(4))) float  float4v;

__device__ __forceinline__ unsigned short f2bf(float f) {
    union { float f; unsigned u; } v; v.f = f;
    unsigned r = v.u + 0x7FFFu + ((v.u >> 16) & 1u);   // RTNE
    return (unsigned short)(r >> 16);
}

__device__ __forceinline__ short8 cvt8(const float* p) {
    float4 u = *reinterpret_cast<const float4*>(p);
    float4 v = *reinterpret_cast<const float4*>(p + 4);
    short8 r;
    r[0] = (short)f2bf(u.x); r[1] = (short)f2bf(u.y);
    r[2] = (short)f2bf(u.z); r[3] = (short)f2bf(u.w);
    r[4] = (short)f2bf(v.x); r[5] = (short)f2bf(v.y);
    r[6] = (short)f2bf(v.z); r[7] = (short)f2bf(v.w);
    return r;
}

__device__ __forceinline__ unsigned long long pack4bf(float a, float b, float c, float d) {
    return (unsigned long long)f2bf(a)
         | ((unsigned long long)f2bf(b) << 16)
         | ((unsigned long long)f2bf(c) << 32)
         | ((unsigned long long)f2bf(d) << 48);
}

__device__ __forceinline__ float sigm(float v)  { return 1.0f / (1.0f + __expf(-v)); }
__device__ __forceinline__ float tanhf_(float v){ return 2.0f / (1.0f + __expf(-2.0f * v)) - 1.0f; }

// ---------------- prepass: x[B][T][I] fp32 -> xfrag[T][chunk16][lane64][8] bf16 ----------------
__global__ __launch_bounds__(256) void build_xfrag(const float* __restrict__ x,
                                                   unsigned short* __restrict__ xf) {
    const int t = blockIdx.x, tid = threadIdx.x;
#pragma unroll
    for (int rep = 0; rep < 4; ++rep) {
        const int eidx  = rep * 256 + tid;
        const int chunk = eidx >> 6, lf = eidx & 63;
        const int kstep = chunk >> 1, nh = chunk & 1;
        const int kq = lf >> 4, nm = lf & 15;
        const int b  = nh * 16 + nm;
        const int i0 = kstep * 32 + kq * 8;
        short8 v = cvt8(x + ((size_t)b * T_ + t) * I_ + i0);
        *reinterpret_cast<short8*>(xf + ((size_t)t * 16 + chunk) * 512 + lf * 8) = v;
    }
}

// ---------------- main persistent kernel (plain launch; 32 blocks co-resident) ----------------
__global__ __launch_bounds__(NT, 1) void bilstm_mfma(
    const float* __restrict__ Wih_f, const float* __restrict__ Whh_f, const float* __restrict__ bias_f,
    const float* __restrict__ Wih_b, const float* __restrict__ Whh_b, const float* __restrict__ bias_b,
    float* __restrict__ out, float* __restrict__ ws) {

    __shared__ __align__(16) char  sAX[16 * 1024];      // x B-frags
    __shared__ __align__(16) char  sAH[32 * 1024];      // h B-frags
    __shared__ __align__(16) float sHT[B_ * HPITCH];    // fp32 h transpose [b][hid_local]

    const int tid  = threadIdx.x;
    const int lane = tid & 63;
    const int w    = tid >> 6;
    const int d    = blockIdx.x & 1;
    const int pb   = blockIdx.x >> 1;

    const unsigned short* xfrag = (const unsigned short*)ws;                     // 8 MB
    unsigned long long* hfrag = (unsigned long long*)((char*)ws + (size_t)T_ * 16 * 1024);
    const char* hfrag_b = (const char*)hfrag;                                    // 256 KB
    unsigned* bar = (unsigned*)((char*)hfrag + (size_t)2 * NSLOT * 32 * 1024);   // [2][T]

    const float* Wih = d ? Wih_b : Wih_f;
    const float* Whh = d ? Whh_b : Whh_f;
    const float* bia = d ? bias_b : bias_f;

    // ---- one-time: weights -> resident A-fragments (bf16) ----
    const int mA  = lane & 15;
    const int kqA = lane >> 4;
    const int gA  = mA & 3;
    const int gr0 = gA * H_ + 32 * pb + 8 * w + (mA >> 2);
    const int gr1 = gr0 + 4;

    short8 wx0[8], wx1[8], wh0[16], wh1[16];
#pragma unroll
    for (int kst = 0; kst < 8; ++kst) {
        wx0[kst] = cvt8(Wih + (size_t)gr0 * I_ + kst * 32 + kqA * 8);
        wx1[kst] = cvt8(Wih + (size_t)gr1 * I_ + kst * 32 + kqA * 8);
    }
#pragma unroll
    for (int kst = 0; kst < 16; ++kst) {
        wh0[kst] = cvt8(Whh + (size_t)gr0 * H_ + kst * 32 + kqA * 8);
        wh1[kst] = cvt8(Whh + (size_t)gr1 * H_ + kst * 32 + kqA * 8);
    }

    const int hid0 = 32 * pb + 8 * w + kqA;          // cell hid (local: 8w+kqA), mt=0
    float4v bq0, bq1;
#pragma unroll
    for (int g = 0; g < 4; ++g) {
        bq0[g] = bia[g * H_ + hid0];
        bq1[g] = bia[g * H_ + hid0 + 4];
    }

    // publisher mapping (tid<128): unit = 8 consecutive hid at fixed batch
    const int pub_b  = tid & 31;
    const int pub_r8 = tid >> 5;                     // 0..3: hid run 8*r8..8*r8+7
    const unsigned pub_chunkL = pb * 2 + (pub_b >> 4);
    const unsigned pub_lf     = pub_r8 * 16 + (pub_b & 15);

    float c00 = 0.f, c01 = 0.f, c10 = 0.f, c11 = 0.f;
    __syncthreads();

    for (int t = 0; t < T_; ++t) {
        const int tx    = d ? (T_ - 1 - t) : t;
        const int slot  = t & (NSLOT - 1);
        const int pslot = (t - 1) & (NSLOT - 1);

        // ---- 1. stage x frags (plain cached loads; immutable data) ----
        {
            const char* src = (const char*)xfrag + ((size_t)tx * 16 + w * 4) * 1024 + lane * 16;
            uint4 xbuf[4];
#pragma unroll
            for (int c = 0; c < 4; ++c) xbuf[c] = *reinterpret_cast<const uint4*>(src + c * 1024);
#pragma unroll
            for (int c = 0; c < 4; ++c)
                *reinterpret_cast<uint4*>(sAX + (w * 4 + c) * 1024 + lane * 16) = xbuf[c];
        }

        // ---- 2. wait for h(t-1) ----
        if (t > 0 && tid == 0) {
            while (__hip_atomic_load(&bar[d * T_ + (t - 1)], __ATOMIC_RELAXED,
                                     __HIP_MEMORY_SCOPE_AGENT) < PB)
                __builtin_amdgcn_s_sleep(1);
        }
        __syncthreads();   // (A)

        // ---- 3a. issue h-frag loads: agent-scope u64 atomics (bypass L1/L2 -> L3 direct) ----
        unsigned long long hbuf[16];
        if (t > 0) {
            const char* src = hfrag_b + ((size_t)(d * NSLOT + pslot) * 32 + w * 8) * 1024 + lane * 16;
#pragma unroll
            for (int c = 0; c < 8; ++c) {
                hbuf[2 * c + 0] = __hip_atomic_load((const unsigned long long*)(src + c * 1024),
                                                    __ATOMIC_RELAXED, __HIP_MEMORY_SCOPE_AGENT);
                hbuf[2 * c + 1] = __hip_atomic_load((const unsigned long long*)(src + c * 1024 + 8),
                                                    __ATOMIC_RELAXED, __HIP_MEMORY_SCOPE_AGENT);
            }
        }

        // ---- 4. MFMA: x part (overlaps h loads in flight) ----
        float4v a00 = bq0, a01 = bq0, a10 = bq1, a11 = bq1;
#pragma unroll
        for (int kst = 0; kst < 8; ++kst) {
            short8 f0 = *reinterpret_cast<const short8*>(sAX + (kst * 2 + 0) * 1024 + lane * 16);
            short8 f1 = *reinterpret_cast<const short8*>(sAX + (kst * 2 + 1) * 1024 + lane * 16);
            a00 = __builtin_amdgcn_mfma_f32_16x16x32_bf16(wx0[kst], f0, a00, 0, 0, 0);
            a01 = __builtin_amdgcn_mfma_f32_16x16x32_bf16(wx0[kst], f1, a01, 0, 0, 0);
            a10 = __builtin_amdgcn_mfma_f32_16x16x32_bf16(wx1[kst], f0, a10, 0, 0, 0);
            a11 = __builtin_amdgcn_mfma_f32_16x16x32_bf16(wx1[kst], f1, a11, 0, 0, 0);
        }

        // ---- 3b. h frags -> LDS ----
        if (t > 0) {
#pragma unroll
            for (int c = 0; c < 8; ++c) {
                char* dst = sAH + (w * 8 + c) * 1024 + lane * 16;
                *reinterpret_cast<unsigned long long*>(dst)     = hbuf[2 * c + 0];
                *reinterpret_cast<unsigned long long*>(dst + 8) = hbuf[2 * c + 1];
            }
        }
        __syncthreads();   // (B)

        // ---- 5. MFMA: h part ----
        if (t > 0) {
#pragma unroll
            for (int kst = 0; kst < 16; ++kst) {
                short8 f0 = *reinterpret_cast<const short8*>(sAH + (kst * 2 + 0) * 1024 + lane * 16);
                short8 f1 = *reinterpret_cast<const short8*>(sAH + (kst * 2 + 1) * 1024 + lane * 16);
                a00 = __builtin_amdgcn_mfma_f32_16x16x32_bf16(wh0[kst], f0, a00, 0, 0, 0);
                a01 = __builtin_amdgcn_mfma_f32_16x16x32_bf16(wh0[kst], f1, a01, 0, 0, 0);
                a10 = __builtin_amdgcn_mfma_f32_16x16x32_bf16(wh1[kst], f0, a10, 0, 0, 0);
                a11 = __builtin_amdgcn_mfma_f32_16x16x32_bf16(wh1[kst], f1, a11, 0, 0, 0);
            }
        }

        // ---- 6. LSTM cell ----
        float h00, h01, h10, h11;
        {
            float iv, fv, gv, ov, c;
            iv = sigm(a00[0]); fv = sigm(a00[1]); gv = tanhf_(a00[2]); ov = sigm(a00[3]);
            c = fv * c00 + iv * gv; c00 = c; h00 = ov * tanhf_(c);
            iv = sigm(a01[0]); fv = sigm(a01[1]); gv = tanhf_(a01[2]); ov = sigm(a01[3]);
            c = fv * c01 + iv * gv; c01 = c; h01 = ov * tanhf_(c);
            iv = sigm(a10[0]); fv = sigm(a10[1]); gv = tanhf_(a10[2]); ov = sigm(a10[3]);
            c = fv * c10 + iv * gv; c10 = c; h10 = ov * tanhf_(c);
            iv = sigm(a11[0]); fv = sigm(a11[1]); gv = tanhf_(a11[2]); ov = sigm(a11[3]);
            c = fv * c11 + iv * gv; c11 = c; h11 = ov * tanhf_(c);
        }

        // ---- 7. transpose h through LDS (fp32): sHT[b][hid_local] ----
        {
            const int hl = 8 * w + kqA;          // hid_local for mt=0
            const int bn = mA;                   // b = nm for h00/h10; +16 for h01/h11
            sHT[(bn)      * HPITCH + hl]     = h00;
            sHT[(bn + 16) * HPITCH + hl]     = h01;
            sHT[(bn)      * HPITCH + hl + 4] = h10;
            sHT[(bn + 16) * HPITCH + hl + 4] = h11;
        }
        __syncthreads();   // (B2) sHT complete

        // ---- 8. publish: 128 lanes, each one 16 B frag unit (2x u64 write-through) ----
        float2 f01, f23, f45, f67;
        if (tid < 128) {
            const float* rp = sHT + pub_b * HPITCH + 8 * pub_r8;
            f01 = *reinterpret_cast<const float2*>(rp + 0);
            f23 = *reinterpret_cast<const float2*>(rp + 2);
            f45 = *reinterpret_cast<const float2*>(rp + 4);
            f67 = *reinterpret_cast<const float2*>(rp + 6);
            const unsigned long long lo = pack4bf(f01.x, f01.y, f23.x, f23.y);
            const unsigned long long hi = pack4bf(f45.x, f45.y, f67.x, f67.y);
            char* dst = (char*)hfrag + ((size_t)((d * NSLOT + slot) * 32 + pub_chunkL)) * 1024
                      + pub_lf * 16;
            __hip_atomic_store((unsigned long long*)dst,       lo, __ATOMIC_RELAXED, __HIP_MEMORY_SCOPE_AGENT);
            __hip_atomic_store((unsigned long long*)(dst + 8), hi, __ATOMIC_RELAXED, __HIP_MEMORY_SCOPE_AGENT);
        }
        __syncthreads();   // (C) vmcnt(0): h publication drained to coherence point

        // ---- 9. arrive ----
        if (tid == 0)
            __hip_atomic_fetch_add(&bar[d * T_ + t], 1u, __ATOMIC_RELAXED,
                                   __HIP_MEMORY_SCOPE_AGENT);

        // ---- 10. out stores (fp32, 32 B contiguous) — after arrive, off critical path ----
        if (tid < 128) {
            float* op = out + ((size_t)pub_b * T_ + tx) * (2 * H_) + (size_t)d * H_
                      + 32 * pb + 8 * pub_r8;
            *reinterpret_cast<float4*>(op + 0) = make_float4(f01.x, f01.y, f23.x, f23.y);
            *reinterpret_cast<float4*>(op + 4) = make_float4(f45.x, f45.y, f67.x, f67.y);
        }
    }
}

extern "C" void kernel_launch(void* const* d_in, const int* in_sizes, int n_in,
                              void* d_out, int out_size, void* d_ws, size_t ws_size,
                              hipStream_t stream) {
    const float* x     = (const float*)d_in[0];
    const float* Wih_f = (const float*)d_in[1];
    const float* Whh_f = (const float*)d_in[2];
    const float* b_f   = (const float*)d_in[3];
    const float* Wih_b = (const float*)d_in[4];
    const float* Whh_b = (const float*)d_in[5];
    const float* b_b   = (const float*)d_in[6];
    float* out = (float*)d_out;

    const size_t xf_bytes = (size_t)T_ * 16 * 1024;          // 8 MB
    const size_t hf_bytes = (size_t)2 * NSLOT * 32 * 1024;   // 256 KB
    const size_t bar_bytes = (size_t)2 * T_ * sizeof(unsigned);

    hipMemsetAsync((char*)d_ws + xf_bytes + hf_bytes, 0, bar_bytes, stream);

    hipLaunchKernelGGL(build_xfrag, dim3(T_), dim3(256), 0, stream,
                       x, (unsigned short*)d_ws);

    hipLaunchKernelGGL(bilstm_mfma, dim3(NBLK), dim3(NT), 0, stream,
                       Wih_f, Whh_f, b_f, Wih_b, Whh_b, b_b, out, (float*)d_ws);
}